// Round 1
// baseline (1805.937 us; speedup 1.0000x reference)
//
#include <hip/hip_runtime.h>
#include <math.h>

#define IN_CAPS 122240
#define T_LEN   7680
#define PW      1918   // pooled width (conv1 out 3836 / 2)
#define HW      1910   // conv2 out width

// ws layout (float offsets)
#define OFF_MX    0        // 64
#define OFF_AV    64       // 64
#define OFF_ATTN  128      // 64
#define OFF_S0    192      // 512  (b,j,p)
#define OFF_S1    704      // 512
#define OFF_S2    1216     // 512
#define OFF_V0    1728     // 512
#define OFF_VSUM  2240     // 512
#define OFF_P     2816     // 2*16*32*1918 = 1964032
#define OFF_H     1966848  // 2*16*32*1910 = 1955840
#define OFF_U     3922688  // 2*122240*8  = 1955840
#define OFF_XHAT  5878528  // 2*122240*256 = 62586880  -> total ~274 MB

// ---------- per-(b,c) max & mean over T ----------
__global__ void k_rowstat(const float* __restrict__ x, float* __restrict__ ws) {
    int row = blockIdx.x;                       // b*32+c, 64 rows
    const float* xr = x + (size_t)row * T_LEN;
    float mx = -INFINITY, sm = 0.f;
    for (int i = threadIdx.x; i < T_LEN; i += 256) {
        float v = xr[i];
        mx = fmaxf(mx, v);
        sm += v;
    }
    __shared__ float smx[256], ssm[256];
    smx[threadIdx.x] = mx; ssm[threadIdx.x] = sm;
    __syncthreads();
    for (int s = 128; s > 0; s >>= 1) {
        if (threadIdx.x < s) {
            smx[threadIdx.x] = fmaxf(smx[threadIdx.x], smx[threadIdx.x + s]);
            ssm[threadIdx.x] += ssm[threadIdx.x + s];
        }
        __syncthreads();
    }
    if (threadIdx.x == 0) {
        ws[OFF_MX + row] = smx[0];
        ws[OFF_AV + row] = ssm[0] * (1.f / (float)T_LEN);
    }
}

// ---------- attn = sigmoid((mx+av) @ Wl^T + 2*bl); also zero S0/S1/S2 ----------
__global__ void k_attn_zero(const float* __restrict__ Wl, const float* __restrict__ bl,
                            float* __restrict__ ws) {
    int t = threadIdx.x;
    for (int i = t; i < 1536; i += 256) ws[OFF_S0 + i] = 0.f;  // S0,S1,S2 contiguous
    if (t < 64) {
        int b = t >> 5, c = t & 31;
        float acc = 2.f * bl[c];
        for (int k = 0; k < 32; k++)
            acc += (ws[OFF_MX + b * 32 + k] + ws[OFF_AV + b * 32 + k]) * Wl[c * 32 + k];
        ws[OFF_ATTN + t] = 1.f / (1.f + expf(-acc));
    }
}

// ---------- conv1 (k=9, stride 2) + bias + ELU + avgpool2 -> p[b][oc][hh][w2] ----------
__global__ void k_conv1pool(const float* __restrict__ x, const float* __restrict__ w1,
                            const float* __restrict__ b1, float* __restrict__ ws) {
    int idx = blockIdx.x * 256 + threadIdx.x;   // exactly 2*16*32*1918 threads
    int w2 = idx % PW;
    int hh = (idx / PW) & 31;
    int oc = (idx / (PW * 32)) & 15;
    int b  = idx / (PW * 32 * 16);
    float a = ws[OFF_ATTN + b * 32 + hh];
    const float* xr = x + ((size_t)b * 32 + hh) * T_LEN + 4 * w2;
    const float* wk = w1 + oc * 9;
    float xv[11];
    #pragma unroll
    for (int k = 0; k < 11; k++) xv[k] = xr[k] * a;
    float o0 = 0.f, o1 = 0.f;
    #pragma unroll
    for (int k = 0; k < 9; k++) { o0 += wk[k] * xv[k]; o1 += wk[k] * xv[k + 2]; }
    o0 += b1[oc]; o1 += b1[oc];
    o0 = o0 > 0.f ? o0 : expm1f(o0);
    o1 = o1 > 0.f ? o1 : expm1f(o1);
    ws[OFF_P + idx] = 0.5f * (o0 + o1);
}

// ---------- conv2 (16ch, k=9, valid) + bias -> h[b][oc][hh][w3] ----------
__global__ void k_conv2(const float* __restrict__ w2, const float* __restrict__ b2,
                        float* __restrict__ ws) {
    int idx = blockIdx.x * 256 + threadIdx.x;   // exactly 2*16*32*1910 threads
    int w3 = idx % HW;
    int hh = (idx / HW) & 31;
    int oc = (idx / (HW * 32)) & 15;
    int b  = idx / (HW * 32 * 16);
    float acc = b2[oc];
    const float* wrow = w2 + oc * 144;
    const float* pb = ws + OFF_P + (size_t)b * 16 * 32 * PW + hh * PW + w3;
    #pragma unroll 4
    for (int ic = 0; ic < 16; ic++) {
        const float* pr = pb + (size_t)ic * 32 * PW;
        #pragma unroll
        for (int k = 0; k < 9; k++) acc += wrow[ic * 9 + k] * pr[k];
    }
    ws[OFF_H + idx] = acc;
}

// ---------- squash groups of 8 (flat reshape) -> u ----------
__global__ void k_squash_u(float* __restrict__ ws) {
    int n = blockIdx.x * 256 + threadIdx.x;     // exactly 2*122240 capsules
    const float4* hp = (const float4*)(ws + OFF_H) + (size_t)n * 2;
    float4 a = hp[0], b = hp[1];
    float ns = a.x*a.x + a.y*a.y + a.z*a.z + a.w*a.w
             + b.x*b.x + b.y*b.y + b.z*b.z + b.w*b.w;
    float nrm = sqrtf(ns);
    float scale = ns / (1.f + ns) / (nrm + 1e-8f);
    a.x *= scale; a.y *= scale; a.z *= scale; a.w *= scale;
    b.x *= scale; b.y *= scale; b.z *= scale; b.w *= scale;
    float4* up = (float4*)(ws + OFF_U) + (size_t)n * 2;
    up[0] = a; up[1] = b;
}

// ---------- x_hat[b][n][j][p] = dot8(Wc[j][n][p][:], u[b][n][:]); S0 += x_hat ----------
// block = 256 threads = all (j,p); each block handles 128 consecutive n. Grid = 955.
__global__ void __launch_bounds__(256) k_xhat(const float* __restrict__ Wc,
                                              float* __restrict__ ws) {
    const int j = threadIdx.x >> 4;
    const int p = threadIdx.x & 15;
    const int n0 = blockIdx.x * 128;
    const float* u = ws + OFF_U;
    float* xhat = ws + OFF_XHAT;
    const size_t wbase = (size_t)j * IN_CAPS * 128 + (size_t)p * 8;
    float sum0 = 0.f, sum1 = 0.f;
    for (int k = 0; k < 128; k++) {
        const int n = n0 + k;
        const float4* wp = (const float4*)(Wc + wbase + (size_t)n * 128);
        float4 wa = wp[0], wb = wp[1];
        const float4* ua = (const float4*)(u + ((size_t)n << 3));
        const float4* ub = (const float4*)(u + ((size_t)(IN_CAPS + n) << 3));
        float4 a0 = ua[0], a1 = ua[1];
        float4 c0 = ub[0], c1 = ub[1];
        float xh0 = wa.x*a0.x + wa.y*a0.y + wa.z*a0.z + wa.w*a0.w
                  + wb.x*a1.x + wb.y*a1.y + wb.z*a1.z + wb.w*a1.w;
        float xh1 = wa.x*c0.x + wa.y*c0.y + wa.z*c0.z + wa.w*c0.w
                  + wb.x*c1.x + wb.y*c1.y + wb.z*c1.z + wb.w*c1.w;
        xhat[((size_t)n << 8) + (j << 4) + p] = xh0;
        xhat[((size_t)(IN_CAPS + n) << 8) + (j << 4) + p] = xh1;
        sum0 += xh0; sum1 += xh1;
    }
    atomicAdd(&ws[OFF_S0 + (j << 4) + p], sum0);
    atomicAdd(&ws[OFF_S0 + 256 + (j << 4) + p], sum1);
}

// ---------- one routing pass: t=v.xh, softmax over j (wave shuffles), s += c*xh ----------
__global__ void __launch_bounds__(256) k_route(const float* __restrict__ xhat,
                                               const float* __restrict__ vin,
                                               float* __restrict__ sout,
                                               int nwaves_per_b) {
    const int tid = threadIdx.x;
    const int wid = tid >> 6;        // 4 waves; b = wid&1
    const int lane = tid & 63;
    const int j = lane >> 2;
    const int pq = lane & 3;
    const int b = wid & 1;
    __shared__ float vsh[512];
    for (int i = tid; i < 512; i += 256) vsh[i] = vin[i];
    __syncthreads();
    const float* vp = &vsh[(((b << 4) + j) << 4) + (pq << 2)];
    const float v0 = vp[0], v1 = vp[1], v2 = vp[2], v3 = vp[3];
    const int wb = (blockIdx.x << 1) + (wid >> 1);    // wave index within b
    const float* xb = xhat + (size_t)b * IN_CAPS * 256;
    float4 acc = make_float4(0.f, 0.f, 0.f, 0.f);
    for (int n = wb; n < IN_CAPS; n += nwaves_per_b) {
        float4 xh = *(const float4*)(xb + ((size_t)n << 8) + (j << 4) + (pq << 2));
        float t = v0 * xh.x + v1 * xh.y + v2 * xh.z + v3 * xh.w;
        t += __shfl_xor(t, 1);
        t += __shfl_xor(t, 2);                 // t_j replicated across 4 lanes
        float tmax = t;
        tmax = fmaxf(tmax, __shfl_xor(tmax, 4));
        tmax = fmaxf(tmax, __shfl_xor(tmax, 8));
        tmax = fmaxf(tmax, __shfl_xor(tmax, 16));
        tmax = fmaxf(tmax, __shfl_xor(tmax, 32));
        float e = expf(t - tmax);
        float es = e;
        es += __shfl_xor(es, 4);
        es += __shfl_xor(es, 8);
        es += __shfl_xor(es, 16);
        es += __shfl_xor(es, 32);
        float c = e / es;
        acc.x += c * xh.x; acc.y += c * xh.y; acc.z += c * xh.z; acc.w += c * xh.w;
    }
    __shared__ float4 accsh[4][64];
    accsh[wid][lane] = acc;
    __syncthreads();
    if (tid < 128) {                           // wid 0 -> b=0 (waves 0,2); wid 1 -> b=1 (1,3)
        float4 a = accsh[wid][lane];
        float4 c = accsh[wid + 2][lane];
        float* dst = sout + (((wid << 4) + j) << 4) + (pq << 2);
        atomicAdd(dst + 0, a.x + c.x);
        atomicAdd(dst + 1, a.y + c.y);
        atomicAdd(dst + 2, a.z + c.z);
        atomicAdd(dst + 3, a.w + c.w);
    }
}

// ---------- v-step: v = squash(s [* 1/16]); mode1: vsum = v0+v; mode2: final output ----------
__global__ void __launch_bounds__(512) k_vstep(float* __restrict__ ws,
                                               const float* __restrict__ wfc,
                                               const float* __restrict__ bfc,
                                               float* __restrict__ out,
                                               int mode) {
    __shared__ float sv[512];
    const int t = threadIdx.x;
    int soff = (mode == 0) ? OFF_S0 : (mode == 1) ? OFF_S1 : OFF_S2;
    float val = ws[soff + t];
    if (mode == 0) val *= (1.f / 16.f);        // uniform c at iter 0
    sv[t] = val;
    __syncthreads();
    const int bj = t >> 4;
    float ns = 0.f;
    #pragma unroll
    for (int p = 0; p < 16; p++) { float q = sv[(bj << 4) + p]; ns += q * q; }
    float nrm = sqrtf(ns);
    float scale = ns / (1.f + ns) / (nrm + 1e-8f);
    float v = scale * val;
    if (mode == 0) {
        ws[OFF_V0 + t] = v;
    } else if (mode == 1) {
        ws[OFF_VSUM + t] = ws[OFF_V0 + t] + v; // b_logits accum == (v0+v1).xhat
    } else {
        __syncthreads();
        sv[t] = v * wfc[t & 255];
        __syncthreads();
        for (int s = 128; s > 0; s >>= 1) {
            if ((t & 255) < s) sv[t] += sv[t + s];
            __syncthreads();
        }
        if ((t & 255) == 0)
            out[t >> 8] = 1.f / (1.f + expf(-(sv[t] + bfc[0])));
    }
}

extern "C" void kernel_launch(void* const* d_in, const int* in_sizes, int n_in,
                              void* d_out, int out_size, void* d_ws, size_t ws_size,
                              hipStream_t stream) {
    const float* x   = (const float*)d_in[0];
    const float* Wl  = (const float*)d_in[1];
    const float* bl  = (const float*)d_in[2];
    const float* W1  = (const float*)d_in[3];
    const float* b1  = (const float*)d_in[4];
    const float* W2  = (const float*)d_in[5];
    const float* b2  = (const float*)d_in[6];
    const float* Wc  = (const float*)d_in[7];
    const float* Wfc = (const float*)d_in[8];
    const float* bfc = (const float*)d_in[9];
    float* out = (float*)d_out;
    float* ws  = (float*)d_ws;

    k_rowstat  <<<64, 256, 0, stream>>>(x, ws);
    k_attn_zero<<<1, 256, 0, stream>>>(Wl, bl, ws);
    k_conv1pool<<<7672, 256, 0, stream>>>(x, W1, b1, ws);   // 2*16*32*1918 / 256
    k_conv2    <<<7640, 256, 0, stream>>>(W2, b2, ws);      // 2*16*32*1910 / 256
    k_squash_u <<<955, 256, 0, stream>>>(ws);               // 2*122240 / 256
    k_xhat     <<<955, 256, 0, stream>>>(Wc, ws);           // 955*128 = 122240 n
    k_vstep    <<<1, 512, 0, stream>>>(ws, Wfc, bfc, out, 0);
    k_route    <<<256, 256, 0, stream>>>(ws + OFF_XHAT, ws + OFF_V0, ws + OFF_S1, 512);
    k_vstep    <<<1, 512, 0, stream>>>(ws, Wfc, bfc, out, 1);
    k_route    <<<256, 256, 0, stream>>>(ws + OFF_XHAT, ws + OFF_VSUM, ws + OFF_S2, 512);
    k_vstep    <<<1, 512, 0, stream>>>(ws, Wfc, bfc, out, 2);
}

// Round 2
// 1461.627 us; speedup vs baseline: 1.2356x; 1.2356x over previous
//
#include <hip/hip_runtime.h>
#include <hip/hip_bf16.h>
#include <math.h>

#define IN_CAPS 122240
#define T_LEN   7680
#define PW      1918   // pooled width (conv1 out 3836 / 2)
#define HW      1910   // conv2 out width

// ws layout (float offsets)
#define OFF_MX    0        // 64
#define OFF_AV    64       // 64
#define OFF_ATTN  128      // 64
#define OFF_S0    192      // 512  (b,j,p)
#define OFF_S1    704      // 512
#define OFF_S2    1216     // 512
#define OFF_V0    1728     // 512
#define OFF_VSUM  2240     // 512
#define OFF_P     2816     // 2*16*32*1918 = 1964032
#define OFF_H     1966848  // 2*16*32*1910 = 1955840
#define OFF_U     3922688  // 2*122240*8  = 1955840
#define OFF_XHAT  5878528  // bf16: 2*122240*256 ushorts = 125 MB

__device__ __forceinline__ float4 bf4_to_f4(ushort4 r) {
    float4 o;
    o.x = __uint_as_float(((unsigned)r.x) << 16);
    o.y = __uint_as_float(((unsigned)r.y) << 16);
    o.z = __uint_as_float(((unsigned)r.z) << 16);
    o.w = __uint_as_float(((unsigned)r.w) << 16);
    return o;
}

// ---------- per-(b,c) max & mean over T ----------
__global__ void k_rowstat(const float* __restrict__ x, float* __restrict__ ws) {
    int row = blockIdx.x;                       // b*32+c, 64 rows
    const float* xr = x + (size_t)row * T_LEN;
    float mx = -INFINITY, sm = 0.f;
    for (int i = threadIdx.x; i < T_LEN; i += 256) {
        float v = xr[i];
        mx = fmaxf(mx, v);
        sm += v;
    }
    __shared__ float smx[256], ssm[256];
    smx[threadIdx.x] = mx; ssm[threadIdx.x] = sm;
    __syncthreads();
    for (int s = 128; s > 0; s >>= 1) {
        if (threadIdx.x < s) {
            smx[threadIdx.x] = fmaxf(smx[threadIdx.x], smx[threadIdx.x + s]);
            ssm[threadIdx.x] += ssm[threadIdx.x + s];
        }
        __syncthreads();
    }
    if (threadIdx.x == 0) {
        ws[OFF_MX + row] = smx[0];
        ws[OFF_AV + row] = ssm[0] * (1.f / (float)T_LEN);
    }
}

// ---------- attn = sigmoid((mx+av) @ Wl^T + 2*bl); also zero S0/S1/S2 ----------
__global__ void k_attn_zero(const float* __restrict__ Wl, const float* __restrict__ bl,
                            float* __restrict__ ws) {
    int t = threadIdx.x;
    for (int i = t; i < 1536; i += 256) ws[OFF_S0 + i] = 0.f;  // S0,S1,S2 contiguous
    if (t < 64) {
        int b = t >> 5, c = t & 31;
        float acc = 2.f * bl[c];
        for (int k = 0; k < 32; k++)
            acc += (ws[OFF_MX + b * 32 + k] + ws[OFF_AV + b * 32 + k]) * Wl[c * 32 + k];
        ws[OFF_ATTN + t] = 1.f / (1.f + expf(-acc));
    }
}

// ---------- conv1 (k=9, stride 2) + bias + ELU + avgpool2 -> p[b][oc][hh][w2] ----------
__global__ void k_conv1pool(const float* __restrict__ x, const float* __restrict__ w1,
                            const float* __restrict__ b1, float* __restrict__ ws) {
    int idx = blockIdx.x * 256 + threadIdx.x;   // exactly 2*16*32*1918 threads
    int w2 = idx % PW;
    int hh = (idx / PW) & 31;
    int oc = (idx / (PW * 32)) & 15;
    int b  = idx / (PW * 32 * 16);
    float a = ws[OFF_ATTN + b * 32 + hh];
    const float* xr = x + ((size_t)b * 32 + hh) * T_LEN + 4 * w2;
    const float* wk = w1 + oc * 9;
    float xv[11];
    #pragma unroll
    for (int k = 0; k < 11; k++) xv[k] = xr[k] * a;
    float o0 = 0.f, o1 = 0.f;
    #pragma unroll
    for (int k = 0; k < 9; k++) { o0 += wk[k] * xv[k]; o1 += wk[k] * xv[k + 2]; }
    o0 += b1[oc]; o1 += b1[oc];
    o0 = o0 > 0.f ? o0 : expm1f(o0);
    o1 = o1 > 0.f ? o1 : expm1f(o1);
    ws[OFF_P + idx] = 0.5f * (o0 + o1);
}

// ---------- conv2 (16ch, k=9, valid) + bias -> h[b][oc][hh][w3] ----------
__global__ void k_conv2(const float* __restrict__ w2, const float* __restrict__ b2,
                        float* __restrict__ ws) {
    int idx = blockIdx.x * 256 + threadIdx.x;   // exactly 2*16*32*1910 threads
    int w3 = idx % HW;
    int hh = (idx / HW) & 31;
    int oc = (idx / (HW * 32)) & 15;
    int b  = idx / (HW * 32 * 16);
    float acc = b2[oc];
    const float* wrow = w2 + oc * 144;
    const float* pb = ws + OFF_P + (size_t)b * 16 * 32 * PW + hh * PW + w3;
    #pragma unroll 4
    for (int ic = 0; ic < 16; ic++) {
        const float* pr = pb + (size_t)ic * 32 * PW;
        #pragma unroll
        for (int k = 0; k < 9; k++) acc += wrow[ic * 9 + k] * pr[k];
    }
    ws[OFF_H + idx] = acc;
}

// ---------- squash groups of 8 (flat reshape) -> u ----------
__global__ void k_squash_u(float* __restrict__ ws) {
    int n = blockIdx.x * 256 + threadIdx.x;     // exactly 2*122240 capsules
    const float4* hp = (const float4*)(ws + OFF_H) + (size_t)n * 2;
    float4 a = hp[0], b = hp[1];
    float ns = a.x*a.x + a.y*a.y + a.z*a.z + a.w*a.w
             + b.x*b.x + b.y*b.y + b.z*b.z + b.w*b.w;
    float nrm = sqrtf(ns);
    float scale = ns / (1.f + ns) / (nrm + 1e-8f);
    a.x *= scale; a.y *= scale; a.z *= scale; a.w *= scale;
    b.x *= scale; b.y *= scale; b.z *= scale; b.w *= scale;
    float4* up = (float4*)(ws + OFF_U) + (size_t)n * 2;
    up[0] = a; up[1] = b;
}

// ---------- x_hat[b][n][j][p] (bf16) = dot8(Wc[j][n][p][:], u[b][n][:]); S0 += x_hat ----
__global__ void __launch_bounds__(256) k_xhat(const float* __restrict__ Wc,
                                              float* __restrict__ ws) {
    const int j = threadIdx.x >> 4;
    const int p = threadIdx.x & 15;
    const int n0 = blockIdx.x * 128;
    const float* u = ws + OFF_U;
    __hip_bfloat16* xhat = (__hip_bfloat16*)(ws + OFF_XHAT);
    const size_t wbase = (size_t)j * IN_CAPS * 128 + (size_t)p * 8;
    float sum0 = 0.f, sum1 = 0.f;
    #pragma unroll 2
    for (int k = 0; k < 128; k++) {
        const int n = n0 + k;
        const float4* wp = (const float4*)(Wc + wbase + (size_t)n * 128);
        float4 wa = wp[0], wb = wp[1];
        const float4* ua = (const float4*)(u + ((size_t)n << 3));
        const float4* ub = (const float4*)(u + ((size_t)(IN_CAPS + n) << 3));
        float4 a0 = ua[0], a1 = ua[1];
        float4 c0 = ub[0], c1 = ub[1];
        float xh0 = wa.x*a0.x + wa.y*a0.y + wa.z*a0.z + wa.w*a0.w
                  + wb.x*a1.x + wb.y*a1.y + wb.z*a1.z + wb.w*a1.w;
        float xh1 = wa.x*c0.x + wa.y*c0.y + wa.z*c0.z + wa.w*c0.w
                  + wb.x*c1.x + wb.y*c1.y + wb.z*c1.z + wb.w*c1.w;
        xhat[((size_t)n << 8) + (j << 4) + p] = __float2bfloat16(xh0);
        xhat[((size_t)(IN_CAPS + n) << 8) + (j << 4) + p] = __float2bfloat16(xh1);
        sum0 += xh0; sum1 += xh1;
    }
    atomicAdd(&ws[OFF_S0 + (j << 4) + p], sum0);
    atomicAdd(&ws[OFF_S0 + 256 + (j << 4) + p], sum1);
}

// ---------- one routing pass over bf16 x_hat ----------
// grid 512: b = blockIdx&1. 4-lane group per capsule, 16 capsules/wave-iter.
// Per capsule: 16 x 8B loads, 2 shuffles per j for the dot, thread-local softmax.
__global__ void __launch_bounds__(256) k_route(const ushort* __restrict__ xhat,
                                               const float* __restrict__ vin,
                                               float* __restrict__ sout) {
    const int tid = threadIdx.x;
    const int lane = tid & 63;
    const int wid = tid >> 6;
    const int q = tid & 3;             // p-quarter
    const int b = blockIdx.x & 1;
    __shared__ float vsh[256];
    __shared__ float red[4][256];
    vsh[tid] = vin[(b << 8) + tid];
    __syncthreads();

    const int g_global = ((blockIdx.x >> 1) << 6) + (tid >> 2);  // 0..16383
    const ushort* xb = xhat + ((size_t)b * IN_CAPS << 8);
    float4 acc[16];
    #pragma unroll
    for (int j = 0; j < 16; j++) acc[j] = make_float4(0.f, 0.f, 0.f, 0.f);

    for (int k = 0; k < 8; k++) {
        const int n = g_global + (k << 14);
        if (n < IN_CAPS) {
            const ushort* base = xb + ((size_t)n << 8) + (q << 2);
            ushort4 raw[16];
            float t[16];
            #pragma unroll
            for (int j = 0; j < 16; j++) {
                raw[j] = *(const ushort4*)(base + (j << 4));
                float4 xf = bf4_to_f4(raw[j]);
                float4 vv = *(const float4*)&vsh[(j << 4) + (q << 2)];
                t[j] = vv.x*xf.x + vv.y*xf.y + vv.z*xf.z + vv.w*xf.w;
            }
            #pragma unroll
            for (int j = 0; j < 16; j++) {
                t[j] += __shfl_xor(t[j], 1);
                t[j] += __shfl_xor(t[j], 2);   // full dot, replicated in 4-lane group
            }
            float tmax = t[0];
            #pragma unroll
            for (int j = 1; j < 16; j++) tmax = fmaxf(tmax, t[j]);
            float e[16]; float es = 0.f;
            #pragma unroll
            for (int j = 0; j < 16; j++) { e[j] = __expf(t[j] - tmax); es += e[j]; }
            float inv = 1.f / es;
            #pragma unroll
            for (int j = 0; j < 16; j++) {
                float c = e[j] * inv;
                float4 xf = bf4_to_f4(raw[j]);
                acc[j].x += c * xf.x; acc[j].y += c * xf.y;
                acc[j].z += c * xf.z; acc[j].w += c * xf.w;
            }
        }
    }
    // reduce the 16 groups of each wave (xor over lane bits 2..5), keep q
    #pragma unroll
    for (int j = 0; j < 16; j++) {
        #pragma unroll
        for (int m = 4; m < 64; m <<= 1) {
            acc[j].x += __shfl_xor(acc[j].x, m);
            acc[j].y += __shfl_xor(acc[j].y, m);
            acc[j].z += __shfl_xor(acc[j].z, m);
            acc[j].w += __shfl_xor(acc[j].w, m);
        }
    }
    if (lane < 4) {
        #pragma unroll
        for (int j = 0; j < 16; j++)
            *(float4*)&red[wid][(j << 4) + (lane << 2)] = acc[j];
    }
    __syncthreads();
    float s = red[0][tid] + red[1][tid] + red[2][tid] + red[3][tid];
    atomicAdd(&sout[(b << 8) + tid], s);
}

// ---------- v-step: v = squash(s [* 1/16]); mode1: vsum = v0+v; mode2: final output ----------
__global__ void __launch_bounds__(512) k_vstep(float* __restrict__ ws,
                                               const float* __restrict__ wfc,
                                               const float* __restrict__ bfc,
                                               float* __restrict__ out,
                                               int mode) {
    __shared__ float sv[512];
    const int t = threadIdx.x;
    int soff = (mode == 0) ? OFF_S0 : (mode == 1) ? OFF_S1 : OFF_S2;
    float val = ws[soff + t];
    if (mode == 0) val *= (1.f / 16.f);        // uniform c at iter 0
    sv[t] = val;
    __syncthreads();
    const int bj = t >> 4;
    float ns = 0.f;
    #pragma unroll
    for (int p = 0; p < 16; p++) { float q = sv[(bj << 4) + p]; ns += q * q; }
    float nrm = sqrtf(ns);
    float scale = ns / (1.f + ns) / (nrm + 1e-8f);
    float v = scale * val;
    if (mode == 0) {
        ws[OFF_V0 + t] = v;
    } else if (mode == 1) {
        ws[OFF_VSUM + t] = ws[OFF_V0 + t] + v; // b_logits accum == (v0+v1).xhat
    } else {
        __syncthreads();
        sv[t] = v * wfc[t & 255];
        __syncthreads();
        for (int s = 128; s > 0; s >>= 1) {
            if ((t & 255) < s) sv[t] += sv[t + s];
            __syncthreads();
        }
        if ((t & 255) == 0)
            out[t >> 8] = 1.f / (1.f + expf(-(sv[t] + bfc[0])));
    }
}

extern "C" void kernel_launch(void* const* d_in, const int* in_sizes, int n_in,
                              void* d_out, int out_size, void* d_ws, size_t ws_size,
                              hipStream_t stream) {
    const float* x   = (const float*)d_in[0];
    const float* Wl  = (const float*)d_in[1];
    const float* bl  = (const float*)d_in[2];
    const float* W1  = (const float*)d_in[3];
    const float* b1  = (const float*)d_in[4];
    const float* W2  = (const float*)d_in[5];
    const float* b2  = (const float*)d_in[6];
    const float* Wc  = (const float*)d_in[7];
    const float* Wfc = (const float*)d_in[8];
    const float* bfc = (const float*)d_in[9];
    float* out = (float*)d_out;
    float* ws  = (float*)d_ws;
    const ushort* xh16 = (const ushort*)(ws + OFF_XHAT);

    k_rowstat  <<<64, 256, 0, stream>>>(x, ws);
    k_attn_zero<<<1, 256, 0, stream>>>(Wl, bl, ws);
    k_conv1pool<<<7672, 256, 0, stream>>>(x, W1, b1, ws);   // 2*16*32*1918 / 256
    k_conv2    <<<7640, 256, 0, stream>>>(W2, b2, ws);      // 2*16*32*1910 / 256
    k_squash_u <<<955, 256, 0, stream>>>(ws);               // 2*122240 / 256
    k_xhat     <<<955, 256, 0, stream>>>(Wc, ws);           // 955*128 = 122240 n
    k_vstep    <<<1, 512, 0, stream>>>(ws, Wfc, bfc, out, 0);
    k_route    <<<512, 256, 0, stream>>>(xh16, ws + OFF_V0, ws + OFF_S1);
    k_vstep    <<<1, 512, 0, stream>>>(ws, Wfc, bfc, out, 1);
    k_route    <<<512, 256, 0, stream>>>(xh16, ws + OFF_VSUM, ws + OFF_S2);
    k_vstep    <<<1, 512, 0, stream>>>(ws, Wfc, bfc, out, 2);
}